// Round 4
// baseline (832.759 us; speedup 1.0000x reference)
//
#include <hip/hip_runtime.h>

typedef __attribute__((ext_vector_type(8))) short short8;
typedef __attribute__((ext_vector_type(16))) float f32x16;

union Frag { short8 v; unsigned u[4]; };

__device__ __forceinline__ unsigned pack_bf16(float lo, float hi) {
    unsigned r;
    asm volatile("v_cvt_pk_bf16_f32 %0, %1, %2" : "=v"(r) : "v"(lo), "v"(hi));
    return r;
}

#define BSHIFT 7
#define BROWS 128            // dst rows per bucket = 1<<BSHIFT
#define MAXNB 1024
#define CHUNK 8192           // edges per hist/scatter block

// ---- k1: per-chunk LDS hist, one global atomic per (block,bucket) ----
__global__ __launch_bounds__(256)
void k_hist(const int* __restrict__ dst, int* __restrict__ ghist, int E, int NB) {
    __shared__ int h[MAXNB];
    const int tid = threadIdx.x;
    for (int b = tid; b < NB; b += 256) h[b] = 0;
    __syncthreads();
    const int c0 = blockIdx.x * CHUNK;
    const int c1 = min(c0 + CHUNK, E);
    for (int i = c0 + tid; i < c1; i += 256) atomicAdd(&h[dst[i] >> BSHIFT], 1);
    __syncthreads();
    for (int b = tid; b < NB; b += 256) {
        const int cnt = h[b];
        if (cnt) atomicAdd(&ghist[b], cnt);
    }
}

// ---- k2: exclusive scan of NB (<1024) bins; writes cursor + base(+total) ----
__global__ __launch_bounds__(1024)
void k_scan(const int* __restrict__ ghist, int* __restrict__ gcursor,
            int* __restrict__ gbase, int NB) {
    __shared__ int wsum[16];
    const int tid = threadIdx.x, lane = tid & 63, wv = tid >> 6;
    const int v = (tid < NB) ? ghist[tid] : 0;
    int s = v;
#pragma unroll
    for (int off = 1; off < 64; off <<= 1) {
        const int t = __shfl_up(s, off, 64);
        if (lane >= off) s += t;
    }
    if (lane == 63) wsum[wv] = s;
    __syncthreads();
    int wbase = 0;
    for (int w = 0; w < wv; ++w) wbase += wsum[w];
    const int excl = wbase + s - v;
    if (tid < NB) { gcursor[tid] = excl; gbase[tid] = excl; }
    if (tid == 1023) gbase[NB] = excl + v;   // total (v==0 here since NB<1024)
}

// ---- k3: claim per (block,bucket) once, slot edges via LDS rtn-atomics ----
__global__ __launch_bounds__(256)
void k_scatter(const int* __restrict__ src, const int* __restrict__ dst,
               const float* __restrict__ cj, int* __restrict__ gcursor,
               int4* __restrict__ recs, int* __restrict__ recs_thin, int fat,
               int E, int NB) {
    __shared__ int cur[MAXNB];
    const int tid = threadIdx.x;
    for (int b = tid; b < NB; b += 256) cur[b] = 0;
    __syncthreads();
    const int c0 = blockIdx.x * CHUNK;
    const int c1 = min(c0 + CHUNK, E);
    for (int i = c0 + tid; i < c1; i += 256) atomicAdd(&cur[dst[i] >> BSHIFT], 1);
    __syncthreads();
    for (int b = tid; b < NB; b += 256) {
        const int cnt = cur[b];
        if (cnt) cur[b] = atomicAdd(&gcursor[b], cnt);  // global base for this block's run
    }
    __syncthreads();
    for (int i = c0 + tid; i < c1; i += 256) {
        const int d = dst[i];
        const int slot = atomicAdd(&cur[d >> BSHIFT], 1);  // LDS rtn-atomic
        if (fat) {
            const int s = src[i];
            recs[slot] = make_int4(i, s, d, __float_as_int(cj[s]));
        } else {
            recs_thin[slot] = i;
        }
    }
}

// ---- k4: one block per bucket; LDS accumulator; zero global atomics ----
__global__ __launch_bounds__(512, 2)
void k_main(const float* __restrict__ weight, const float* __restrict__ prob_w,
            const float* __restrict__ rscore_w, const float* __restrict__ review_w,
            const float* __restrict__ feat, const float* __restrict__ cj,
            const float* __restrict__ ci, const int* __restrict__ src_idx,
            const int* __restrict__ dst_idx,
            const int4* __restrict__ recs, const int* __restrict__ recs_thin, int fat,
            const int* __restrict__ gbase, float* __restrict__ out, int N_DST)
{
    __shared__ float accs[BROWS * 64];   // 32 KB
    const int tid = threadIdx.x;
    float4* acc4 = (float4*)accs;
#pragma unroll
    for (int it = 0; it < 4; ++it) acc4[tid + it * 512] = float4{0.f, 0.f, 0.f, 0.f};

    const int lane = tid & 63;
    const int h = lane >> 5;     // k-half
    const int c = lane & 31;     // col within tile
    const int w = tid >> 6;      // wave id 0..7
    const int b = blockIdx.x;
    const int start = gbase[b];
    const int end = gbase[b + 1];

    const float4* rw4 = reinterpret_cast<const float4*>(review_w);
    const float4* pw4 = reinterpret_cast<const float4*>(prob_w);
    const float4* sw4 = reinterpret_cast<const float4*>(rscore_w);
    const float4* ft4 = reinterpret_cast<const float4*>(feat);

    // B fragments: B[k][o] = review_w[o][k]; lane holds col o=32t+c, k=16s+8h+j
    Frag bf[2][4];
#pragma unroll
    for (int t = 0; t < 2; ++t) {
#pragma unroll
        for (int s = 0; s < 4; ++s) {
            const float4 r0 = rw4[(32 * t + c) * 16 + 4 * s + 2 * h];
            const float4 r1 = rw4[(32 * t + c) * 16 + 4 * s + 2 * h + 1];
            bf[t][s].u[0] = pack_bf16(r0.x, r0.y);
            bf[t][s].u[1] = pack_bf16(r0.z, r0.w);
            bf[t][s].u[2] = pack_bf16(r1.x, r1.y);
            bf[t][s].u[3] = pack_bf16(r1.z, r1.w);
        }
    }

    __syncthreads();   // acc zero visible before any ds_add

    const int nbt = (end - start + 31) >> 5;
    for (int bt = w; bt < nbt; bt += 8) {
        const int idx = start + bt * 32 + c;
        const bool valid = idx < end;
        int eid = 0, se = 0, dl = 0;
        float cjv = 0.0f;
        if (fat) {
            if (valid) {
                const int4 r = recs[idx];
                eid = r.x; se = r.y; dl = r.z & (BROWS - 1);
                cjv = __int_as_float(r.w);
            }
        } else {
            if (valid) {
                eid = recs_thin[idx];
                se = src_idx[eid];
                dl = dst_idx[eid] & (BROWS - 1);
                cjv = cj[se];
            }
        }

        // ---- A fragments (feat rows) + f32 gate partial dots ----
        Frag af[4];
        float px = 0.0f, sx = 0.0f;
#pragma unroll
        for (int s = 0; s < 4; ++s) {
            const size_t base = (size_t)eid * 16 + 4 * s + 2 * h;
            const float4 f0 = ft4[base];
            const float4 f1 = ft4[base + 1];
            const float4 p0 = pw4[4 * s + 2 * h];
            const float4 p1 = pw4[4 * s + 2 * h + 1];
            const float4 q0 = sw4[4 * s + 2 * h];
            const float4 q1 = sw4[4 * s + 2 * h + 1];
            px += f0.x * p0.x + f0.y * p0.y + f0.z * p0.z + f0.w * p0.w
                + f1.x * p1.x + f1.y * p1.y + f1.z * p1.z + f1.w * p1.w;
            sx += f0.x * q0.x + f0.y * q0.y + f0.z * q0.z + f0.w * q0.w
                + f1.x * q1.x + f1.y * q1.y + f1.z * q1.z + f1.w * q1.w;
            af[s].u[0] = pack_bf16(f0.x, f0.y);
            af[s].u[1] = pack_bf16(f0.z, f0.w);
            af[s].u[2] = pack_bf16(f1.x, f1.y);
            af[s].u[3] = pack_bf16(f1.z, f1.w);
        }

        px += __shfl_xor(px, 32, 64);
        sx += __shfl_xor(sx, 32, 64);
        const float pa = __fdividef(1.0f, 1.0f + __expf(-px));
        const float gs = __fdividef(1.0f, 1.0f + __expf(-sx));
        const float Ae = pa * cjv;   // scales weight[src] (0 for invalid lanes)
        const float Be = gs * cjv;   // scales rf

        // ---- MFMA: rf_raw[32 edges][64 outs] ----
        f32x16 acc0 = {0.0f};
        f32x16 acc1 = {0.0f};
#pragma unroll
        for (int s = 0; s < 4; ++s) {
            acc0 = __builtin_amdgcn_mfma_f32_32x32x16_bf16(af[s].v, bf[0][s].v, acc0, 0, 0, 0);
            acc1 = __builtin_amdgcn_mfma_f32_32x32x16_bf16(af[s].v, bf[1][s].v, acc1, 0, 0, 0);
        }

        // ---- epilogue: D row e=(r&3)+8*(r>>2)+4h, col=c; accumulate to LDS ----
#pragma unroll
        for (int r = 0; r < 16; ++r) {
            const int e_lr = (r & 3) + 8 * (r >> 2) + 4 * h;
            const float Ar = __shfl(Ae, e_lr, 64);
            const float Br = __shfl(Be, e_lr, 64);
            const int sr = __shfl(se, e_lr, 64);
            const int dr = __shfl(dl, e_lr, 64);
            const float w0 = weight[sr * 64 + c];
            const float w1 = weight[sr * 64 + 32 + c];
            const float m0 = acc0[r] * Br + w0 * Ar;
            const float m1 = acc1[r] * Br + w1 * Ar;
            atomicAdd(&accs[dr * 64 + c], m0);        // ds_add_f32
            atomicAdd(&accs[dr * 64 + 32 + c], m1);
        }
    }

    __syncthreads();

    // ---- writeout: rows [b*128, b*128+128) exclusively owned; plain stores ----
    const int rowbase = b << BSHIFT;
#pragma unroll
    for (int it = 0; it < 4; ++it) {
        const int i4 = tid + it * 512;       // float4 index, 2048 total
        const int row = i4 >> 4;
        const int g = rowbase + row;
        if (g < N_DST) {
            const float s = ci[g];
            float4 v = acc4[i4];
            v.x *= s; v.y *= s; v.z *= s; v.w *= s;
            reinterpret_cast<float4*>(out)[(size_t)g * 16 + (i4 & 15)] = v;
        }
    }
}

extern "C" void kernel_launch(void* const* d_in, const int* in_sizes, int n_in,
                              void* d_out, int out_size, void* d_ws, size_t ws_size,
                              hipStream_t stream) {
    const float* weight    = (const float*)d_in[0];
    const float* prob_w    = (const float*)d_in[1];
    const float* rscore_w  = (const float*)d_in[2];
    const float* review_w  = (const float*)d_in[3];
    const float* feat      = (const float*)d_in[4];
    const float* cj        = (const float*)d_in[5];
    const float* ci        = (const float*)d_in[6];
    const int*   src_idx   = (const int*)d_in[7];
    const int*   dst_idx   = (const int*)d_in[8];
    float* out = (float*)d_out;
    const int E = in_sizes[7];
    const int N_DST = in_sizes[6];
    const int NB = (N_DST + BROWS - 1) >> BSHIFT;   // 782 for N_DST=100000

    // ws layout: ghist[1024] | gcursor[1024] | gbase[1025] | pad | recs
    int* ghist   = (int*)d_ws;
    int* gcursor = ghist + 1024;
    int* gbase   = ghist + 2048;
    const size_t rec_off = 16384;
    const size_t need_fat  = rec_off + (size_t)E * sizeof(int4);
    const size_t need_thin = rec_off + (size_t)E * sizeof(int);
    const int fat = (ws_size >= need_fat) ? 1 : 0;
    int4* recs      = (int4*)((char*)d_ws + rec_off);
    int*  recs_thin = (int*)((char*)d_ws + rec_off);

    hipMemsetAsync(ghist, 0, 1024 * sizeof(int), stream);

    const int nchunk = (E + CHUNK - 1) / CHUNK;
    k_hist<<<nchunk, 256, 0, stream>>>(dst_idx, ghist, E, NB);
    k_scan<<<1, 1024, 0, stream>>>(ghist, gcursor, gbase, NB);
    k_scatter<<<nchunk, 256, 0, stream>>>(src_idx, dst_idx, cj, gcursor,
                                          recs, recs_thin, fat, E, NB);
    k_main<<<NB, 512, 0, stream>>>(weight, prob_w, rscore_w, review_w, feat,
                                   cj, ci, src_idx, dst_idx,
                                   recs, recs_thin, fat, gbase, out, N_DST);
}

// Round 5
// 798.051 us; speedup vs baseline: 1.0435x; 1.0435x over previous
//
#include <hip/hip_runtime.h>

typedef __attribute__((ext_vector_type(8))) short short8;
typedef __attribute__((ext_vector_type(16))) float f32x16;

union Frag { short8 v; unsigned u[4]; };

__device__ __forceinline__ unsigned pack_bf16(float lo, float hi) {
    unsigned r;
    asm volatile("v_cvt_pk_bf16_f32 %0, %1, %2" : "=v"(r) : "v"(lo), "v"(hi));
    return r;
}

#define BSHIFT 5
#define BROWS 32             // dst rows per bucket
#define MAXNB 4096
#define CHUNK 32768          // edges per hist/scatter block

// ---- k1: per-chunk LDS hist, one global atomic per (block,bucket) ----
__global__ __launch_bounds__(256)
void k_hist(const int* __restrict__ dst, int* __restrict__ ghist, int E, int NB) {
    __shared__ int h[MAXNB];
    const int tid = threadIdx.x;
    for (int b = tid; b < NB; b += 256) h[b] = 0;
    __syncthreads();
    const int c0 = blockIdx.x * CHUNK;
    const int c1 = min(c0 + CHUNK, E);
    for (int i = c0 + tid; i < c1; i += 256) atomicAdd(&h[dst[i] >> BSHIFT], 1);
    __syncthreads();
    for (int b = tid; b < NB; b += 256) {
        const int cnt = h[b];
        if (cnt) atomicAdd(&ghist[b], cnt);
    }
}

// ---- k2: exclusive scan of NB (<=4096) bins -> gcursor, gbase; gbase[NB]=E ----
__global__ __launch_bounds__(1024)
void k_scan(const int* __restrict__ ghist, int* __restrict__ gcursor,
            int* __restrict__ gbase, int NB, int E) {
    __shared__ int wsum[16];
    const int tid = threadIdx.x, lane = tid & 63, wv = tid >> 6;
    const int i0 = tid * 4;
    int4 v = {0, 0, 0, 0};
    // ghist is zero-padded to MAXNB, so a full int4 load is safe
    v = *reinterpret_cast<const int4*>(ghist + i0);
    const int s0 = v.x, s1 = s0 + v.y, s2 = s1 + v.z, s3 = s2 + v.w;
    int s = s3;
#pragma unroll
    for (int off = 1; off < 64; off <<= 1) {
        const int t = __shfl_up(s, off, 64);
        if (lane >= off) s += t;
    }
    if (lane == 63) wsum[wv] = s;
    __syncthreads();
    int wbase = 0;
    for (int w = 0; w < wv; ++w) wbase += wsum[w];
    const int tb = wbase + s - s3;
    const int o0 = tb, o1 = tb + s0, o2 = tb + s1, o3 = tb + s2;
    if (i0 + 0 < NB) { gcursor[i0 + 0] = o0; gbase[i0 + 0] = o0; }
    if (i0 + 1 < NB) { gcursor[i0 + 1] = o1; gbase[i0 + 1] = o1; }
    if (i0 + 2 < NB) { gcursor[i0 + 2] = o2; gbase[i0 + 2] = o2; }
    if (i0 + 3 < NB) { gcursor[i0 + 3] = o3; gbase[i0 + 3] = o3; }
    if (tid == 0) gbase[NB] = E;
}

// ---- k3: claim once per (block,bucket); slot via LDS rtn-atomics ----
__global__ __launch_bounds__(256)
void k_scatter(const int* __restrict__ src, const int* __restrict__ dst,
               int* __restrict__ gcursor,
               int2* __restrict__ recs, int* __restrict__ recs_thin, int fat,
               int E, int NB) {
    __shared__ int cur[MAXNB];
    const int tid = threadIdx.x;
    for (int b = tid; b < NB; b += 256) cur[b] = 0;
    __syncthreads();
    const int c0 = blockIdx.x * CHUNK;
    const int c1 = min(c0 + CHUNK, E);
    for (int i = c0 + tid; i < c1; i += 256) atomicAdd(&cur[dst[i] >> BSHIFT], 1);
    __syncthreads();
    for (int b = tid; b < NB; b += 256) {
        const int cnt = cur[b];
        if (cnt) cur[b] = atomicAdd(&gcursor[b], cnt);
    }
    __syncthreads();
    for (int i = c0 + tid; i < c1; i += 256) {
        const int d = dst[i];
        const int slot = atomicAdd(&cur[d >> BSHIFT], 1);
        if (fat) {
            recs[slot] = make_int2(i, src[i] | ((d & (BROWS - 1)) << 20));
        } else {
            recs_thin[slot] = i;
        }
    }
}

// ---- k4: one block (256 thr, 4 waves) per 32-row bucket; LDS accumulator ----
__global__ __launch_bounds__(256, 4)
void k_main(const float* __restrict__ weight, const float* __restrict__ prob_w,
            const float* __restrict__ rscore_w, const float* __restrict__ review_w,
            const float* __restrict__ feat, const float* __restrict__ cj,
            const float* __restrict__ ci, const int* __restrict__ src_idx,
            const int* __restrict__ dst_idx,
            const int2* __restrict__ recs, const int* __restrict__ recs_thin, int fat,
            const int* __restrict__ gbase, float* __restrict__ out, int N_DST)
{
    __shared__ float accs[BROWS * 64];   // 8 KB
    const int tid = threadIdx.x;
    float4* acc4 = (float4*)accs;
#pragma unroll
    for (int it = 0; it < 2; ++it) acc4[tid + it * 256] = float4{0.f, 0.f, 0.f, 0.f};

    const int lane = tid & 63;
    const int h = lane >> 5;     // k-half
    const int c = lane & 31;     // col within tile
    const int w = tid >> 6;      // wave id 0..3
    const int b = blockIdx.x;
    const int start = gbase[b];
    const int end = gbase[b + 1];

    const float4* rw4 = reinterpret_cast<const float4*>(review_w);
    const float4* pw4 = reinterpret_cast<const float4*>(prob_w);
    const float4* sw4 = reinterpret_cast<const float4*>(rscore_w);
    const float4* ft4 = reinterpret_cast<const float4*>(feat);

    // B fragments: B[k][o] = review_w[o][k]; lane holds col o=32t+c, k=16s+8h+j
    Frag bf[2][4];
#pragma unroll
    for (int t = 0; t < 2; ++t) {
#pragma unroll
        for (int s = 0; s < 4; ++s) {
            const float4 r0 = rw4[(32 * t + c) * 16 + 4 * s + 2 * h];
            const float4 r1 = rw4[(32 * t + c) * 16 + 4 * s + 2 * h + 1];
            bf[t][s].u[0] = pack_bf16(r0.x, r0.y);
            bf[t][s].u[1] = pack_bf16(r0.z, r0.w);
            bf[t][s].u[2] = pack_bf16(r1.x, r1.y);
            bf[t][s].u[3] = pack_bf16(r1.z, r1.w);
        }
    }

    __syncthreads();   // acc zero visible before any ds_add

    const int nbt = (end - start + 31) >> 5;
    for (int bt = w; bt < nbt; bt += 4) {
        const int idx = start + bt * 32 + c;
        const bool valid = idx < end;
        int eid = 0, se = 0, dl = 0;
        float cjv = 0.0f;
        if (fat) {
            if (valid) {
                const int2 r = recs[idx];
                eid = r.x;
                se = r.y & 0xFFFFF;
                dl = (r.y >> 20) & (BROWS - 1);
                cjv = cj[se];
            }
        } else {
            if (valid) {
                eid = recs_thin[idx];
                se = src_idx[eid];
                dl = dst_idx[eid] & (BROWS - 1);
                cjv = cj[se];
            }
        }

        // ---- A fragments (feat rows) + f32 gate partial dots ----
        Frag af[4];
        float px = 0.0f, sx = 0.0f;
#pragma unroll
        for (int s = 0; s < 4; ++s) {
            const size_t base = (size_t)eid * 16 + 4 * s + 2 * h;
            const float4 f0 = ft4[base];
            const float4 f1 = ft4[base + 1];
            const float4 p0 = pw4[4 * s + 2 * h];
            const float4 p1 = pw4[4 * s + 2 * h + 1];
            const float4 q0 = sw4[4 * s + 2 * h];
            const float4 q1 = sw4[4 * s + 2 * h + 1];
            px += f0.x * p0.x + f0.y * p0.y + f0.z * p0.z + f0.w * p0.w
                + f1.x * p1.x + f1.y * p1.y + f1.z * p1.z + f1.w * p1.w;
            sx += f0.x * q0.x + f0.y * q0.y + f0.z * q0.z + f0.w * q0.w
                + f1.x * q1.x + f1.y * q1.y + f1.z * q1.z + f1.w * q1.w;
            af[s].u[0] = pack_bf16(f0.x, f0.y);
            af[s].u[1] = pack_bf16(f0.z, f0.w);
            af[s].u[2] = pack_bf16(f1.x, f1.y);
            af[s].u[3] = pack_bf16(f1.z, f1.w);
        }

        px += __shfl_xor(px, 32, 64);
        sx += __shfl_xor(sx, 32, 64);
        const float pa = __fdividef(1.0f, 1.0f + __expf(-px));
        const float gs = __fdividef(1.0f, 1.0f + __expf(-sx));
        const float Ae = pa * cjv;   // scales weight[src] (0 for invalid lanes)
        const float Be = gs * cjv;   // scales rf

        // ---- MFMA: rf_raw[32 edges][64 outs] ----
        f32x16 acc0 = {0.0f};
        f32x16 acc1 = {0.0f};
#pragma unroll
        for (int s = 0; s < 4; ++s) {
            acc0 = __builtin_amdgcn_mfma_f32_32x32x16_bf16(af[s].v, bf[0][s].v, acc0, 0, 0, 0);
            acc1 = __builtin_amdgcn_mfma_f32_32x32x16_bf16(af[s].v, bf[1][s].v, acc1, 0, 0, 0);
        }

        // ---- epilogue: D row e=(r&3)+8*(r>>2)+4h, col=c; accumulate to LDS ----
#pragma unroll
        for (int r = 0; r < 16; ++r) {
            const int e_lr = (r & 3) + 8 * (r >> 2) + 4 * h;
            const float Ar = __shfl(Ae, e_lr, 64);
            const float Br = __shfl(Be, e_lr, 64);
            const int sr = __shfl(se, e_lr, 64);
            const int dr = __shfl(dl, e_lr, 64);
            const float w0 = weight[sr * 64 + c];
            const float w1 = weight[sr * 64 + 32 + c];
            const float m0 = acc0[r] * Br + w0 * Ar;
            const float m1 = acc1[r] * Br + w1 * Ar;
            atomicAdd(&accs[dr * 64 + c], m0);        // ds_add_f32
            atomicAdd(&accs[dr * 64 + 32 + c], m1);
        }
    }

    __syncthreads();

    // ---- writeout: rows [b*32, b*32+32) exclusively owned; plain stores ----
    const int rowbase = b << BSHIFT;
#pragma unroll
    for (int it = 0; it < 2; ++it) {
        const int i4 = tid + it * 256;       // float4 index, 512 total
        const int row = i4 >> 4;
        const int g = rowbase + row;
        if (g < N_DST) {
            const float s = ci[g];
            float4 v = acc4[i4];
            v.x *= s; v.y *= s; v.z *= s; v.w *= s;
            reinterpret_cast<float4*>(out)[(size_t)g * 16 + (i4 & 15)] = v;
        }
    }
}

extern "C" void kernel_launch(void* const* d_in, const int* in_sizes, int n_in,
                              void* d_out, int out_size, void* d_ws, size_t ws_size,
                              hipStream_t stream) {
    const float* weight    = (const float*)d_in[0];
    const float* prob_w    = (const float*)d_in[1];
    const float* rscore_w  = (const float*)d_in[2];
    const float* review_w  = (const float*)d_in[3];
    const float* feat      = (const float*)d_in[4];
    const float* cj        = (const float*)d_in[5];
    const float* ci        = (const float*)d_in[6];
    const int*   src_idx   = (const int*)d_in[7];
    const int*   dst_idx   = (const int*)d_in[8];
    float* out = (float*)d_out;
    const int E = in_sizes[7];
    const int N_DST = in_sizes[6];
    const int N_SRC = in_sizes[0] / 64;
    const int NB = (N_DST + BROWS - 1) >> BSHIFT;   // 3125 for N_DST=100000

    // ws layout: ghist[4096] | gcursor[4096] | gbase[4097] | pad | recs
    int* ghist   = (int*)d_ws;
    int* gcursor = ghist + 4096;
    int* gbase   = ghist + 8192;
    const size_t rec_off = 65536;
    const size_t need_fat  = rec_off + (size_t)E * sizeof(int2);
    const int fat = (ws_size >= need_fat && N_SRC <= (1 << 20)) ? 1 : 0;
    int2* recs      = (int2*)((char*)d_ws + rec_off);
    int*  recs_thin = (int*)((char*)d_ws + rec_off);

    hipMemsetAsync(ghist, 0, 4096 * sizeof(int), stream);

    const int nchunk = (E + CHUNK - 1) / CHUNK;
    k_hist<<<nchunk, 256, 0, stream>>>(dst_idx, ghist, E, NB);
    k_scan<<<1, 1024, 0, stream>>>(ghist, gcursor, gbase, NB, E);
    k_scatter<<<nchunk, 256, 0, stream>>>(src_idx, dst_idx, gcursor,
                                          recs, recs_thin, fat, E, NB);
    k_main<<<NB, 256, 0, stream>>>(weight, prob_w, rscore_w, review_w, feat,
                                   cj, ci, src_idx, dst_idx,
                                   recs, recs_thin, fat, gbase, out, N_DST);
}

// Round 6
// 323.181 us; speedup vs baseline: 2.5768x; 2.4694x over previous
//
#include <hip/hip_runtime.h>

typedef __attribute__((ext_vector_type(8))) short short8;
typedef __attribute__((ext_vector_type(16))) float f32x16;

union Frag { short8 v; unsigned u[4]; };

__device__ __forceinline__ unsigned pack_bf16(float lo, float hi) {
    unsigned r;
    asm volatile("v_cvt_pk_bf16_f32 %0, %1, %2" : "=v"(r) : "v"(lo), "v"(hi));
    return r;
}

#define BSHIFT 7
#define BROWS 128            // dst rows per bucket (exclusively owned by one block)
#define MAXNB 1024
#define CHUNK 8192           // edges per hist/scatter block (196 blocks for E=1.6M)
#define CAP 2560             // LDS record capacity per bucket (mean 2048, +11 sigma)

// ---- k1: per-chunk LDS hist, one global atomic per (block,bucket) ----
__global__ __launch_bounds__(256)
void k_hist(const int* __restrict__ dst, int* __restrict__ ghist, int E, int NB) {
    __shared__ int h[MAXNB];
    const int tid = threadIdx.x;
    for (int b = tid; b < NB; b += 256) h[b] = 0;
    __syncthreads();
    const int c0 = blockIdx.x * CHUNK;
    const int c1 = min(c0 + CHUNK, E);
    for (int i = c0 + tid; i < c1; i += 256) atomicAdd(&h[dst[i] >> BSHIFT], 1);
    __syncthreads();
    for (int b = tid; b < NB; b += 256) {
        const int cnt = h[b];
        if (cnt) atomicAdd(&ghist[b], cnt);
    }
}

// ---- k2: exclusive scan of NB (<=1024) bins -> gcursor, gbase; gbase[NB]=E ----
__global__ __launch_bounds__(256)
void k_scan(const int* __restrict__ ghist, int* __restrict__ gcursor,
            int* __restrict__ gbase, int NB, int E) {
    __shared__ int wsum[4];
    const int tid = threadIdx.x, lane = tid & 63, wv = tid >> 6;
    const int i0 = tid * 4;                       // covers 1024 (ghist zero-padded)
    const int4 v = *reinterpret_cast<const int4*>(ghist + i0);
    const int s0 = v.x, s1 = s0 + v.y, s2 = s1 + v.z, s3 = s2 + v.w;
    int s = s3;
#pragma unroll
    for (int off = 1; off < 64; off <<= 1) {
        const int t = __shfl_up(s, off, 64);
        if (lane >= off) s += t;
    }
    if (lane == 63) wsum[wv] = s;
    __syncthreads();
    int wbase = 0;
    for (int w = 0; w < wv; ++w) wbase += wsum[w];
    const int tb = wbase + s - s3;
    if (i0 + 0 < NB) { gcursor[i0 + 0] = tb;      gbase[i0 + 0] = tb; }
    if (i0 + 1 < NB) { gcursor[i0 + 1] = tb + s0; gbase[i0 + 1] = tb + s0; }
    if (i0 + 2 < NB) { gcursor[i0 + 2] = tb + s1; gbase[i0 + 2] = tb + s1; }
    if (i0 + 3 < NB) { gcursor[i0 + 3] = tb + s2; gbase[i0 + 3] = tb + s2; }
    if (tid == 0) gbase[NB] = E;
}

// ---- k3: claim once per (block,bucket); slot via LDS rtn-atomics; fat recs ----
__global__ __launch_bounds__(256)
void k_scatter(const int* __restrict__ src, const int* __restrict__ dst,
               int* __restrict__ gcursor, int2* __restrict__ recs,
               int E, int NB, int packed) {
    __shared__ int cur[MAXNB];
    const int tid = threadIdx.x;
    for (int b = tid; b < NB; b += 256) cur[b] = 0;
    __syncthreads();
    const int c0 = blockIdx.x * CHUNK;
    const int c1 = min(c0 + CHUNK, E);
    for (int i = c0 + tid; i < c1; i += 256) atomicAdd(&cur[dst[i] >> BSHIFT], 1);
    __syncthreads();
    for (int b = tid; b < NB; b += 256) {
        const int cnt = cur[b];
        if (cnt) cur[b] = atomicAdd(&gcursor[b], cnt);
    }
    __syncthreads();
    for (int i = c0 + tid; i < c1; i += 256) {
        const int d = dst[i];
        const int slot = atomicAdd(&cur[d >> BSHIFT], 1);
        const int lo = packed ? (src[i] & 0xFFFFF) : 0;
        recs[slot] = make_int2(i, lo | ((d & (BROWS - 1)) << 20));
    }
}

// ---- shared batch body: 32 edges -> MFMA -> run-length epilogue w/ carry ----
__device__ __forceinline__ void batch_body(
    int eid, int se, int d, float cjci,
    const Frag bf[2][4],
    const float4* __restrict__ pw4, const float4* __restrict__ sw4,
    const float4* __restrict__ ft4,
    const float* __restrict__ weight, float* __restrict__ out,
    int h, int c, int& prev_d, float& r0acc, float& r1acc)
{
    // A fragments (feat rows) + f32 gate partial dots
    Frag af[4];
    float px = 0.0f, sx = 0.0f;
#pragma unroll
    for (int s = 0; s < 4; ++s) {
        const size_t base = (size_t)eid * 16 + 4 * s + 2 * h;
        const float4 f0 = ft4[base];
        const float4 f1 = ft4[base + 1];
        const float4 p0 = pw4[4 * s + 2 * h];
        const float4 p1 = pw4[4 * s + 2 * h + 1];
        const float4 q0 = sw4[4 * s + 2 * h];
        const float4 q1 = sw4[4 * s + 2 * h + 1];
        px += f0.x * p0.x + f0.y * p0.y + f0.z * p0.z + f0.w * p0.w
            + f1.x * p1.x + f1.y * p1.y + f1.z * p1.z + f1.w * p1.w;
        sx += f0.x * q0.x + f0.y * q0.y + f0.z * q0.z + f0.w * q0.w
            + f1.x * q1.x + f1.y * q1.y + f1.z * q1.z + f1.w * q1.w;
        af[s].u[0] = pack_bf16(f0.x, f0.y);
        af[s].u[1] = pack_bf16(f0.z, f0.w);
        af[s].u[2] = pack_bf16(f1.x, f1.y);
        af[s].u[3] = pack_bf16(f1.z, f1.w);
    }

    px += __shfl_xor(px, 32, 64);
    sx += __shfl_xor(sx, 32, 64);
    const float pa = __fdividef(1.0f, 1.0f + __expf(-px));
    const float gs = __fdividef(1.0f, 1.0f + __expf(-sx));
    const float Ae = pa * cjci;     // scales weight[src] (0 for invalid lanes)
    const float Be = gs * cjci;     // scales rf

    f32x16 acc0 = {0.0f};
    f32x16 acc1 = {0.0f};
#pragma unroll
    for (int s = 0; s < 4; ++s) {
        acc0 = __builtin_amdgcn_mfma_f32_32x32x16_bf16(af[s].v, bf[0][s].v, acc0, 0, 0, 0);
        acc1 = __builtin_amdgcn_mfma_f32_32x32x16_bf16(af[s].v, bf[1][s].v, acc1, 0, 0, 0);
    }

    // epilogue: D row e=(r&3)+8*(r>>2)+4h, col=c; run-length flush, carry across calls
#pragma unroll
    for (int r = 0; r < 16; ++r) {
        const int e_lr = (r & 3) + 8 * (r >> 2) + 4 * h;
        const float Ar = __shfl(Ae, e_lr, 64);
        const float Br = __shfl(Be, e_lr, 64);
        const int sr = __shfl(se, e_lr, 64);
        const int dr = __shfl(d, e_lr, 64);
        const float w0 = weight[sr * 64 + c];
        const float w1 = weight[sr * 64 + 32 + c];
        const float m0 = acc0[r] * Br + w0 * Ar;
        const float m1 = acc1[r] * Br + w1 * Ar;
        if (__any(dr != prev_d)) {
            if (dr != prev_d) {
                if (prev_d >= 0) {
                    unsafeAtomicAdd(&out[(size_t)prev_d * 64 + c], r0acc);
                    unsafeAtomicAdd(&out[(size_t)prev_d * 64 + 32 + c], r1acc);
                }
                r0acc = 0.0f;
                r1acc = 0.0f;
                prev_d = dr;
            }
        }
        r0acc += m0;
        r1acc += m1;
    }
}

// ---- k4: one block per 128-dst bucket; in-LDS counting sort; L2-local atomics ----
__global__ __launch_bounds__(256, 4)
void k_main(const float* __restrict__ weight, const float* __restrict__ prob_w,
            const float* __restrict__ rscore_w, const float* __restrict__ review_w,
            const float* __restrict__ feat, const float* __restrict__ cj,
            const float* __restrict__ ci, const int* __restrict__ src_idx,
            const int2* __restrict__ recs, const int* __restrict__ gbase,
            float* __restrict__ out, int packed)
{
    __shared__ int2 srecs[CAP];                 // 20480 B
    __shared__ unsigned short order[CAP];       //  5120 B
    __shared__ int bins[BROWS];                 //   512 B

    const int tid = threadIdx.x;
    const int lane = tid & 63;
    const int h = lane >> 5;
    const int c = lane & 31;
    const int w = tid >> 6;
    const int b = blockIdx.x;
    const int start = gbase[b];
    const int end = gbase[b + 1];
    const int total = end - start;
    const int count = min(total, CAP);
    const int rowbase = b << BSHIFT;

    // ---- phase 1: load + counting sort by dst-local (no overlap with hot loop) ----
    for (int i = tid; i < count; i += 256) srecs[i] = recs[start + i];
    if (tid < BROWS) bins[tid] = 0;
    __syncthreads();
    for (int i = tid; i < count; i += 256)
        atomicAdd(&bins[(srecs[i].y >> 20) & (BROWS - 1)], 1);
    __syncthreads();
    if (tid < 64) {
        const int b0 = bins[tid], b1 = bins[64 + tid];
        int s0 = b0;
#pragma unroll
        for (int off = 1; off < 64; off <<= 1) {
            const int t = __shfl_up(s0, off, 64);
            if (lane >= off) s0 += t;
        }
        const int tot0 = __shfl(s0, 63, 64);
        int s1 = b1;
#pragma unroll
        for (int off = 1; off < 64; off <<= 1) {
            const int t = __shfl_up(s1, off, 64);
            if (lane >= off) s1 += t;
        }
        bins[tid] = s0 - b0;                    // exclusive bases -> cursors
        bins[64 + tid] = tot0 + s1 - b1;
    }
    __syncthreads();
    for (int i = tid; i < count; i += 256) {
        const int dl = (srecs[i].y >> 20) & (BROWS - 1);
        order[atomicAdd(&bins[dl], 1)] = (unsigned short)i;
    }

    // B fragments while sort settles
    const float4* rw4 = reinterpret_cast<const float4*>(review_w);
    const float4* pw4 = reinterpret_cast<const float4*>(prob_w);
    const float4* sw4 = reinterpret_cast<const float4*>(rscore_w);
    const float4* ft4 = reinterpret_cast<const float4*>(feat);
    Frag bf[2][4];
#pragma unroll
    for (int t = 0; t < 2; ++t) {
#pragma unroll
        for (int s = 0; s < 4; ++s) {
            const float4 r0 = rw4[(32 * t + c) * 16 + 4 * s + 2 * h];
            const float4 r1 = rw4[(32 * t + c) * 16 + 4 * s + 2 * h + 1];
            bf[t][s].u[0] = pack_bf16(r0.x, r0.y);
            bf[t][s].u[1] = pack_bf16(r0.z, r0.w);
            bf[t][s].u[2] = pack_bf16(r1.x, r1.y);
            bf[t][s].u[3] = pack_bf16(r1.z, r1.w);
        }
    }
    __syncthreads();

    // ---- phase 2: contiguous span per wave over sorted edges; carry runs ----
    const int nbt = (count + 31) >> 5;
    const int q = nbt >> 2, rr = nbt & 3;
    const int bt0 = w * q + min(w, rr);
    const int bt1 = bt0 + q + (w < rr ? 1 : 0);

    int prev_d = -1;
    float r0acc = 0.0f, r1acc = 0.0f;
    for (int bt = bt0; bt < bt1; ++bt) {
        const int idx = (bt << 5) + c;
        const bool valid = idx < count;
        const int i = valid ? (int)order[idx] : 0;
        const int2 rec = srecs[i];
        const int eid = rec.x;
        const int se = packed ? (rec.y & 0xFFFFF) : src_idx[eid];
        const int d = rowbase + ((rec.y >> 20) & (BROWS - 1));
        const float cjci = valid ? cj[se] * ci[d] : 0.0f;
        batch_body(eid, se, d, cjci, bf, pw4, sw4, ft4, weight, out,
                   h, c, prev_d, r0acc, r1acc);
    }
    if (prev_d >= 0) {
        unsafeAtomicAdd(&out[(size_t)prev_d * 64 + c], r0acc);
        unsafeAtomicAdd(&out[(size_t)prev_d * 64 + 32 + c], r1acc);
    }

    // ---- overflow (total > CAP, ~never): unsorted from global, per-batch runs ----
    if (total > CAP) {
        const int nob = (total - CAP + 31) >> 5;
        for (int bt = w; bt < nob; bt += 4) {
            const int gidx = start + CAP + (bt << 5) + c;
            const bool valid = gidx < end;
            const int2 rec = recs[valid ? gidx : start];
            const int eid = rec.x;
            const int se = packed ? (rec.y & 0xFFFFF) : src_idx[eid];
            const int d = rowbase + ((rec.y >> 20) & (BROWS - 1));
            const float cjci = valid ? cj[se] * ci[d] : 0.0f;
            int pd = -1;
            float a0 = 0.0f, a1 = 0.0f;
            batch_body(eid, se, d, cjci, bf, pw4, sw4, ft4, weight, out,
                       h, c, pd, a0, a1);
            if (pd >= 0) {
                unsafeAtomicAdd(&out[(size_t)pd * 64 + c], a0);
                unsafeAtomicAdd(&out[(size_t)pd * 64 + 32 + c], a1);
            }
        }
    }
}

// ---- fallback (ws too small): R2-style direct kernel ----
__global__ __launch_bounds__(256, 2)
void k_direct(const float* __restrict__ weight, const float* __restrict__ prob_w,
              const float* __restrict__ rscore_w, const float* __restrict__ review_w,
              const float* __restrict__ feat, const float* __restrict__ cj,
              const float* __restrict__ ci, const int* __restrict__ src_idx,
              const int* __restrict__ dst_idx, float* __restrict__ out, int E)
{
    const int lane = threadIdx.x & 63;
    const int h = lane >> 5, c = lane & 31;
    const int wid = blockIdx.x * (blockDim.x >> 6) + (threadIdx.x >> 6);
    const int nw = gridDim.x * (blockDim.x >> 6);
    const float4* rw4 = reinterpret_cast<const float4*>(review_w);
    const float4* pw4 = reinterpret_cast<const float4*>(prob_w);
    const float4* sw4 = reinterpret_cast<const float4*>(rscore_w);
    const float4* ft4 = reinterpret_cast<const float4*>(feat);
    Frag bf[2][4];
#pragma unroll
    for (int t = 0; t < 2; ++t)
#pragma unroll
        for (int s = 0; s < 4; ++s) {
            const float4 r0 = rw4[(32 * t + c) * 16 + 4 * s + 2 * h];
            const float4 r1 = rw4[(32 * t + c) * 16 + 4 * s + 2 * h + 1];
            bf[t][s].u[0] = pack_bf16(r0.x, r0.y);
            bf[t][s].u[1] = pack_bf16(r0.z, r0.w);
            bf[t][s].u[2] = pack_bf16(r1.x, r1.y);
            bf[t][s].u[3] = pack_bf16(r1.z, r1.w);
        }
    const int ntot = (E + 31) >> 5;
    for (int bt = wid; bt < ntot; bt += nw) {
        const int idx = (bt << 5) + c;
        const bool valid = idx < E;
        const int eid = valid ? idx : 0;
        const int se = src_idx[eid];
        const int d = dst_idx[eid];
        const float cjci = valid ? cj[se] * ci[d] : 0.0f;
        int pd = -1;
        float a0 = 0.0f, a1 = 0.0f;
        batch_body(eid, se, d, cjci, bf, pw4, sw4, ft4, weight, out,
                   h, c, pd, a0, a1);
        if (pd >= 0) {
            unsafeAtomicAdd(&out[(size_t)pd * 64 + c], a0);
            unsafeAtomicAdd(&out[(size_t)pd * 64 + 32 + c], a1);
        }
    }
}

extern "C" void kernel_launch(void* const* d_in, const int* in_sizes, int n_in,
                              void* d_out, int out_size, void* d_ws, size_t ws_size,
                              hipStream_t stream) {
    const float* weight    = (const float*)d_in[0];
    const float* prob_w    = (const float*)d_in[1];
    const float* rscore_w  = (const float*)d_in[2];
    const float* review_w  = (const float*)d_in[3];
    const float* feat      = (const float*)d_in[4];
    const float* cj        = (const float*)d_in[5];
    const float* ci        = (const float*)d_in[6];
    const int*   src_idx   = (const int*)d_in[7];
    const int*   dst_idx   = (const int*)d_in[8];
    float* out = (float*)d_out;
    const int E = in_sizes[7];
    const int N_DST = in_sizes[6];
    const int N_SRC = in_sizes[0] / 64;
    const int NB = (N_DST + BROWS - 1) >> BSHIFT;   // 782 for N_DST=100000

    hipMemsetAsync(d_out, 0, (size_t)out_size * sizeof(float), stream);

    // ws layout: ghist[1024] | gcursor[1024] | gbase[1025] | pad->16KB | recs int2[E]
    const size_t rec_off = 16384;
    const size_t need = rec_off + (size_t)E * sizeof(int2);
    if (ws_size < need || NB > MAXNB) {
        k_direct<<<2048, 256, 0, stream>>>(weight, prob_w, rscore_w, review_w, feat,
                                           cj, ci, src_idx, dst_idx, out, E);
        return;
    }
    int* ghist   = (int*)d_ws;
    int* gcursor = ghist + 1024;
    int* gbase   = ghist + 2048;
    int2* recs   = (int2*)((char*)d_ws + rec_off);
    const int packed = (N_SRC <= (1 << 20)) ? 1 : 0;

    hipMemsetAsync(ghist, 0, 1024 * sizeof(int), stream);

    const int nchunk = (E + CHUNK - 1) / CHUNK;
    k_hist<<<nchunk, 256, 0, stream>>>(dst_idx, ghist, E, NB);
    k_scan<<<1, 256, 0, stream>>>(ghist, gcursor, gbase, NB, E);
    k_scatter<<<nchunk, 256, 0, stream>>>(src_idx, dst_idx, gcursor, recs, E, NB, packed);
    k_main<<<NB, 256, 0, stream>>>(weight, prob_w, rscore_w, review_w, feat,
                                   cj, ci, src_idx, recs, gbase, out, packed);
}